// Round 4
// baseline (410.590 us; speedup 1.0000x reference)
//
#include <hip/hip_runtime.h>
#include <hip/hip_bf16.h>

#define B_  16
#define C_  256
#define H_  48
#define W_  64
#define ND  21           // displacements per axis
#define HW  (H_ * W_)
#define CHW (C_ * H_ * W_)
#define GRP 7            // dyi per block (3 groups of 7)

typedef __attribute__((ext_vector_type(8))) short bf16x8;
typedef __attribute__((ext_vector_type(4))) float f32x4;

__device__ __forceinline__ unsigned int bf16rtne(float f) {
  unsigned int u = __builtin_bit_cast(unsigned int, f);
  return (u + 0x7fffu + ((u >> 16) & 1u)) >> 16;
}

// ---------------------------------------------------------------------------
// Kernel 1: fp32 NCHW -> bf16 NHWC. grid = 2*B*H = 1536 blocks, 256 thr.
// (unchanged from round 3; gap analysis says it's not the bottleneck)
// ---------------------------------------------------------------------------
__global__ __launch_bounds__(256) void transpose_cvt(
    const float* __restrict__ in1, const float* __restrict__ in2,
    unsigned short* __restrict__ o1, unsigned short* __restrict__ o2) {
  __shared__ unsigned short T[256 * 66];   // [c][x], stride 66 (odd word stride)

  int blk = blockIdx.x;
  const float* in = in1;
  unsigned short* op = o1;
  if (blk >= B_ * H_) { blk -= B_ * H_; in = in2; op = o2; }
  int y = blk % H_;
  int b = blk / H_;
  int t = threadIdx.x;

  int u  = t & 15;          // x-quad: x = 4u..4u+3
  int cb = t >> 4;          // c base 0..15, c = cb + 16r
  const float* src = in + (long)b * CHW + y * W_ + u * 4;
#pragma unroll
  for (int r = 0; r < 16; r++) {
    int c = cb + 16 * r;
    float4 v = *(const float4*)(src + (long)c * HW);
    unsigned int p0 = bf16rtne(v.x) | (bf16rtne(v.y) << 16);
    unsigned int p1 = bf16rtne(v.z) | (bf16rtne(v.w) << 16);
    unsigned int* Tw = (unsigned int*)(T + c * 66 + u * 4);
    Tw[0] = p0;
    Tw[1] = p1;
  }
  __syncthreads();

  int x  = t >> 2;          // pixel 0..63
  int cq = t & 3;           // c-chunk
  unsigned short* orow = op + (((long)(b * H_ + y) * W_ + x) * C_);
#pragma unroll
  for (int g = 0; g < 8; g++) {
    int gg = (g + cq) & 7;
    int c0 = cq * 64 + gg * 8;
    unsigned int w[4];
#pragma unroll
    for (int k2 = 0; k2 < 4; k2++) {
      unsigned int lo = T[(c0 + 2 * k2) * 66 + x];
      unsigned int hi = T[(c0 + 2 * k2 + 1) * 66 + x];
      w[k2] = lo | (hi << 16);
    }
    *(uint4*)(orow + c0) = *(uint4*)w;
  }
}

// ---------------------------------------------------------------------------
// Kernel 2: correlation v3. grid = 3 * B*H = 2304 blocks, 256 thr (4 waves).
// Block (g,b,y) handles dyi in [7g, 7g+7). Wave w owns n-tile xp=[16w,16w+16)
// x all 64 m-rows: A-frags live in 64 VGPRs for all 7 dyi; per dyi the wave
// reads only its 8 b128 B-frags from LDS (B row read exactly once per block).
// Band epilogue goes through LDS Sband[21][67] -> 21 fully-coalesced 256B
// stores per dyi (+ fused re-zero). 2 barriers per valid dyi.
// LDS: 32KB Bbuf + 5.6KB Sband -> 4 blocks/CU; launch_bounds(256,4).
// ---------------------------------------------------------------------------
__global__ __launch_bounds__(256, 4) void corr_kernel(
    const unsigned short* __restrict__ At, const unsigned short* __restrict__ Bt,
    float* __restrict__ out) {
  __shared__ __align__(16) unsigned short Bbuf[64 * 256];   // 32KB, XOR-swizzled
  __shared__ float Sband[ND * 67];                          // [dxi][x], stride 67

  int blk  = blockIdx.x;
  int y    = blk % H_;
  int b    = (blk / H_) & 15;
  int g    = blk / (B_ * H_);            // dyi group, slowest -> L2 locality in (b,y)
  int t    = threadIdx.x;
  int lane = t & 63;
  int wave = t >> 6;
  int l15  = lane & 15;
  int quad = lane >> 4;

  // zero the band buffer (thread-local ownership, no barrier needed yet)
  for (int i = t; i < ND * 67; i += 256) Sband[i] = 0.0f;

  // ---- stage A row via Bbuf, pull fragments to registers ----
  const unsigned short* Ab = At + (long)(b * H_ + y) * W_ * C_;
#pragma unroll
  for (int k = 0; k < 8; k++) {
    int f = t + 256 * k;                 // 16B granule 0..2047
    int row = f >> 5, col = f & 31;
    uint4 v = ((const uint4*)Ab)[f];
    *(uint4*)(Bbuf + row * 256 + ((col ^ (row & 7)) << 3)) = v;
  }
  __syncthreads();

  bf16x8 afrag[4][8];                    // A[m=16mt+l15][k=(4ks+quad)*8+j]
#pragma unroll
  for (int mt = 0; mt < 4; mt++) {
    int row = mt * 16 + l15;
#pragma unroll
    for (int ks = 0; ks < 8; ks++)
      afrag[mt][ks] =
          *(const bf16x8*)(Bbuf + row * 256 + (((ks * 4 + quad) ^ (row & 7)) << 3));
  }
  __syncthreads();                       // Bbuf free for B staging

  int xp = 16 * wave + l15;              // this wave's n-column

  for (int j = 0; j < GRP; j++) {
    int dyi = g * GRP + j;
    int y2 = y + 2 * dyi - 20;           // block-uniform
    long outBase = ((long)(b * (ND * ND) + dyi * ND) * H_ + y) * W_;

    if (y2 < 0 || y2 >= H_) {
      // zero slab: 21 channels x 64 x, coalesced
      for (int i = t; i < ND * W_; i += 256) {
        int dxi = i >> 6, x = i & 63;
        out[outBase + (long)dxi * HW + x] = 0.0f;
      }
      continue;
    }

    // ---- stage B row (coalesced global -> swizzled LDS) ----
    const unsigned short* Bb = Bt + (long)(b * H_ + y2) * W_ * C_;
#pragma unroll
    for (int k = 0; k < 8; k++) {
      int f = t + 256 * k;
      int row = f >> 5, col = f & 31;
      uint4 v = ((const uint4*)Bb)[f];
      *(uint4*)(Bbuf + row * 256 + ((col ^ (row & 7)) << 3)) = v;
    }
    __syncthreads();                     // barrier A: B visible, prev stores done

    f32x4 acc[4];
#pragma unroll
    for (int mt = 0; mt < 4; mt++) acc[mt] = (f32x4){0.f, 0.f, 0.f, 0.f};

#pragma unroll
    for (int ks = 0; ks < 8; ks++) {
      int row = 16 * wave + l15;
      bf16x8 bf =
          *(const bf16x8*)(Bbuf + row * 256 + (((ks * 4 + quad) ^ (l15 & 7)) << 3));
#pragma unroll
      for (int mt = 0; mt < 4; mt++)
        acc[mt] = __builtin_amdgcn_mfma_f32_16x16x32_bf16(afrag[mt][ks], bf,
                                                          acc[mt], 0, 0, 0);
    }

    // ---- epilogue: C/D col=l15 (-> xp), row=quad*4+r (-> x); band to Sband ----
#pragma unroll
    for (int mt = 0; mt < 4; mt++) {
#pragma unroll
      for (int r = 0; r < 4; r++) {
        int x = 16 * mt + 4 * quad + r;
        int dx = xp - x;
        if (dx >= -20 && dx <= 20 && !(dx & 1))
          Sband[((dx + 20) >> 1) * 67 + x] = acc[mt][r] * (1.0f / 256.0f);
      }
    }
    __syncthreads();                     // barrier B: Sband complete, b-reads done

    // ---- coalesced store (21 x 256B segments) + fused re-zero ----
    for (int i = t; i < ND * W_; i += 256) {
      int dxi = i >> 6, x = i & 63;
      out[outBase + (long)dxi * HW + x] = Sband[dxi * 67 + x];
      Sband[dxi * 67 + x] = 0.0f;
    }
  }
}

// ---------------------------------------------------------------------------
extern "C" void kernel_launch(void* const* d_in, const int* in_sizes, int n_in,
                              void* d_out, int out_size, void* d_ws, size_t ws_size,
                              hipStream_t stream) {
  (void)in_sizes; (void)n_in; (void)out_size; (void)ws_size;
  const float* in1 = (const float*)d_in[0];
  const float* in2 = (const float*)d_in[1];
  float* out = (float*)d_out;

  unsigned short* o1 = (unsigned short*)d_ws;                    // bf16 [B,H,W,C]
  unsigned short* o2 = o1 + (size_t)B_ * H_ * W_ * C_;           // bf16 [B,H,W,C]

  transpose_cvt<<<2 * B_ * H_, 256, 0, stream>>>(in1, in2, o1, o2);
  corr_kernel<<<3 * B_ * H_, 256, 0, stream>>>(o1, o2, out);
}

// Round 5
// 266.412 us; speedup vs baseline: 1.5412x; 1.5412x over previous
//
#include <hip/hip_runtime.h>
#include <hip/hip_bf16.h>

#define B_  16
#define C_  256
#define H_  48
#define W_  64
#define ND  21           // displacements per axis
#define HW  (H_ * W_)
#define CHW (C_ * H_ * W_)

typedef __attribute__((ext_vector_type(8))) short bf16x8;
typedef __attribute__((ext_vector_type(4))) float f32x4;

__device__ __forceinline__ unsigned int bf16rtne(float f) {
  unsigned int u = __builtin_bit_cast(unsigned int, f);
  return (u + 0x7fffu + ((u >> 16) & 1u)) >> 16;
}

// ---------------------------------------------------------------------------
// Kernel 1: fp32 NCHW -> bf16 FRAGMENT-MAJOR layout, per (b,y) row (32KB):
//   granule G = ks*256 + t16*64 + quad*16 + l15   (16B granules)
//   content  = bf16 src[x = t16*16+l15][k = ks*32+quad*8 .. +8)
// so corr's MFMA fragment load (ks,t16) is ONE contiguous 1KB segment with
// lane i at base+16i. grid = 2*B*H = 1536 blocks, 256 thr.
// ---------------------------------------------------------------------------
__global__ __launch_bounds__(256) void transpose_cvt(
    const float* __restrict__ in1, const float* __restrict__ in2,
    unsigned short* __restrict__ o1, unsigned short* __restrict__ o2) {
  __shared__ unsigned short T[256 * 66];   // [c][x], stride 66 (odd word stride)

  int blk = blockIdx.x;
  const float* in = in1;
  unsigned short* op = o1;
  if (blk >= B_ * H_) { blk -= B_ * H_; in = in2; op = o2; }
  int y = blk % H_;
  int b = blk / H_;
  int t = threadIdx.x;

  // ---- phase 1: global fp32 -> bf16 -> LDS[c][x] ----
  int u  = t & 15;          // x-quad: x = 4u..4u+3
  int cb = t >> 4;          // c base 0..15, c = cb + 16r
  const float* src = in + (long)b * CHW + y * W_ + u * 4;
#pragma unroll
  for (int r = 0; r < 16; r++) {
    int c = cb + 16 * r;
    float4 v = *(const float4*)(src + (long)c * HW);
    unsigned int p0 = bf16rtne(v.x) | (bf16rtne(v.y) << 16);
    unsigned int p1 = bf16rtne(v.z) | (bf16rtne(v.w) << 16);
    unsigned int* Tw = (unsigned int*)(T + c * 66 + u * 4);
    Tw[0] = p0;
    Tw[1] = p1;
  }
  __syncthreads();

  // ---- phase 2: LDS gather -> fragment-major 16B stores (4x256B/instr) ----
  int x   = t >> 2;         // pixel 0..63
  int cq  = t & 3;
  int t16 = x >> 4, xl = x & 15;
  unsigned short* orow = op + (long)(b * H_ + y) * (W_ * C_);
#pragma unroll
  for (int g = 0; g < 8; g++) {
    int gg = (g + cq) & 7;              // bank-spread rotation
    int kg = cq * 8 + gg;               // k-granule 0..31
    int c0 = kg * 8;                    // first channel of this granule
    unsigned int wv[4];
#pragma unroll
    for (int k2 = 0; k2 < 4; k2++) {
      unsigned int lo = T[(c0 + 2 * k2) * 66 + x];
      unsigned int hi = T[(c0 + 2 * k2 + 1) * 66 + x];
      wv[k2] = lo | (hi << 16);
    }
    int ks = kg >> 2, qd = kg & 3;
    int G = ks * 256 + t16 * 64 + qd * 16 + xl;
    *(uint4*)(orow + (long)G * 8) = *(uint4*)wv;
  }
}

// ---------------------------------------------------------------------------
// Kernel 2: correlation v5 — NO LDS, NO barriers. grid = B*H = 768, 256 thr.
// Wave w: m-half mh=w&1 (x in [32mh,32mh+32)), n-half nh=w>>1.
// afrag[2][8] (64 VGPR) persists across all 21 dyi. Per dyi: 16 contiguous
// 1KB B-frag loads (ks-pipelined), <=32 MFMA 16x16x32 (tile pairs with
// |ntile-mtile|<=2 only), band-extract via precomputed per-lane offsets.
// VGPR ~140 -> launch_bounds(256,3): 3 blocks/CU, whole grid resident.
// ---------------------------------------------------------------------------
__global__ __launch_bounds__(256, 3) void corr_kernel(
    const unsigned short* __restrict__ A2, const unsigned short* __restrict__ B2,
    float* __restrict__ out) {
  int blk  = blockIdx.x;
  int y    = blk % H_;
  int b    = blk / H_;
  int t    = threadIdx.x;
  int lane = t & 63;
  int w    = t >> 6;
  int l15  = lane & 15;
  int quad = lane >> 4;
  int mh   = w & 1;
  int nh   = w >> 1;

  // ---- A fragments: 1KB contiguous loads, live in registers for all dyi ----
  const unsigned short* rowA = A2 + (long)(b * H_ + y) * (W_ * C_);
  bf16x8 afrag[2][8];
#pragma unroll
  for (int mtl = 0; mtl < 2; mtl++) {
    int mtg = mh * 2 + mtl;
#pragma unroll
    for (int ks = 0; ks < 8; ks++)
      afrag[mtl][ks] = *(const bf16x8*)(rowA + ks * 2048 + mtg * 512 + lane * 8);
  }

  // ---- per-lane store offsets (dyi-invariant): dxi*HW + x, or -1 ----
  int soff[2][2][4];
#pragma unroll
  for (int mtl = 0; mtl < 2; mtl++)
#pragma unroll
    for (int ntl = 0; ntl < 2; ntl++)
#pragma unroll
      for (int r = 0; r < 4; r++) {
        int xx = (mh * 2 + mtl) * 16 + quad * 4 + r;
        int xp = (nh * 2 + ntl) * 16 + l15;
        int dx = xp - xx;
        soff[mtl][ntl][r] =
            (dx >= -20 && dx <= 20 && !(dx & 1)) ? (((dx + 20) >> 1) * HW + xx) : -1;
      }

  // tile-pair liveness (wave-uniform): |16*(ntg-mtg)| <= 35
  bool live[2][2];
#pragma unroll
  for (int mtl = 0; mtl < 2; mtl++)
#pragma unroll
    for (int ntl = 0; ntl < 2; ntl++) {
      int diff = (nh * 2 + ntl) - (mh * 2 + mtl);
      live[mtl][ntl] = (diff >= -2 && diff <= 2);
    }

  float* ob = out + (long)b * (ND * ND * HW) + y * W_;

  for (int dyi = 0; dyi < ND; dyi++) {
    int y2 = y + 2 * dyi - 20;                       // block-uniform
    float* od = ob + (long)dyi * (ND * HW);

    if (y2 < 0 || y2 >= H_) {                        // zero slab (y padding)
      for (int i = t; i < ND * W_; i += 256)
        od[(i >> 6) * HW + (i & 63)] = 0.0f;
      continue;
    }

    const unsigned short* rowB = B2 + (long)(b * H_ + y2) * (W_ * C_);
    f32x4 acc[2][2];
#pragma unroll
    for (int mtl = 0; mtl < 2; mtl++)
#pragma unroll
      for (int ntl = 0; ntl < 2; ntl++) acc[mtl][ntl] = (f32x4){0.f, 0.f, 0.f, 0.f};

    // ks-pipelined B-frag stream: each load = one contiguous 1KB segment
    bf16x8 bc0 = *(const bf16x8*)(rowB + (nh * 2 + 0) * 512 + lane * 8);
    bf16x8 bc1 = *(const bf16x8*)(rowB + (nh * 2 + 1) * 512 + lane * 8);
#pragma unroll
    for (int ks = 0; ks < 8; ks++) {
      int ksn = (ks < 7) ? ks + 1 : 0;               // clamp: no OOB read
      bf16x8 bn0 = *(const bf16x8*)(rowB + ksn * 2048 + (nh * 2 + 0) * 512 + lane * 8);
      bf16x8 bn1 = *(const bf16x8*)(rowB + ksn * 2048 + (nh * 2 + 1) * 512 + lane * 8);
#pragma unroll
      for (int mtl = 0; mtl < 2; mtl++) {
        if (live[mtl][0])
          acc[mtl][0] = __builtin_amdgcn_mfma_f32_16x16x32_bf16(afrag[mtl][ks], bc0,
                                                                acc[mtl][0], 0, 0, 0);
        if (live[mtl][1])
          acc[mtl][1] = __builtin_amdgcn_mfma_f32_16x16x32_bf16(afrag[mtl][ks], bc1,
                                                                acc[mtl][1], 0, 0, 0);
      }
      bc0 = bn0;
      bc1 = bn1;
    }

    // ---- band-extract stores (precomputed offsets, exec-masked) ----
#pragma unroll
    for (int mtl = 0; mtl < 2; mtl++)
#pragma unroll
      for (int ntl = 0; ntl < 2; ntl++)
#pragma unroll
        for (int r = 0; r < 4; r++) {
          int so = soff[mtl][ntl][r];
          if (so >= 0) od[so] = acc[mtl][ntl][r] * (1.0f / 256.0f);
        }

    // ---- edge zeros (x+dx outside [0,W)) ----
    if (w == 0) {
#pragma unroll
      for (int dxi = 0; dxi < 10; dxi++) {
        int cnt = 20 - 2 * dxi;
        if (lane < cnt) od[dxi * HW + lane] = 0.0f;
      }
    } else if (w == 3) {
#pragma unroll
      for (int dxi = 11; dxi < ND; dxi++) {
        int dx = 2 * dxi - 20;
        if (lane < dx) od[dxi * HW + (W_ - dx) + lane] = 0.0f;
      }
    }
  }
}

// ---------------------------------------------------------------------------
extern "C" void kernel_launch(void* const* d_in, const int* in_sizes, int n_in,
                              void* d_out, int out_size, void* d_ws, size_t ws_size,
                              hipStream_t stream) {
  (void)in_sizes; (void)n_in; (void)out_size; (void)ws_size;
  const float* in1 = (const float*)d_in[0];
  const float* in2 = (const float*)d_in[1];
  float* out = (float*)d_out;

  unsigned short* o1 = (unsigned short*)d_ws;                    // bf16 frag-major
  unsigned short* o2 = o1 + (size_t)B_ * H_ * W_ * C_;           // bf16 frag-major

  transpose_cvt<<<2 * B_ * H_, 256, 0, stream>>>(in1, in2, o1, o2);
  corr_kernel<<<B_ * H_, 256, 0, stream>>>(o1, o2, out);
}